// Round 1
// baseline (3230.039 us; speedup 1.0000x reference)
//
#include <hip/hip_runtime.h>
#include <cstddef>

// ---------------------------------------------------------------------------
// init node embedding: out[n][o] = b[o] + sum_k in[n][k] * W[k][o]
// ---------------------------------------------------------------------------
__global__ __launch_bounds__(256) void init_embed_kernel(
    const float* __restrict__ in, const float* __restrict__ W,
    const float* __restrict__ b, float* __restrict__ out, int N, int Kin)
{
  int idx = blockIdx.x * 256 + threadIdx.x;
  if (idx >= N * 64) return;
  int n = idx >> 6, o = idx & 63;
  float acc = b[o];
  const float* row = in + (size_t)n * Kin;
  for (int k = 0; k < Kin; k++) acc += row[k] * W[k * 64 + o];
  out[idx] = acc;
}

// ---------------------------------------------------------------------------
// GINE message + aggregate: agg[dst] += relu(x[src] + (attr @ We + be))
// one thread per (edge, dim); edge embedding recomputed inline (10 FMAs)
// ---------------------------------------------------------------------------
__global__ __launch_bounds__(256) void gine_msg_kernel(
    const float* __restrict__ x, const float* __restrict__ attr,
    const float* __restrict__ We, const float* __restrict__ be,
    const int* __restrict__ ei, float* __restrict__ agg, int E)
{
  int idx = blockIdx.x * 256 + threadIdx.x;
  if (idx >= E * 64) return;
  int e = idx >> 6, d = idx & 63;
  int src = ei[e];
  int dst = ei[E + e];
  float ea = be[d];
  const float* arow = attr + (size_t)e * 10;
  #pragma unroll
  for (int k = 0; k < 10; k++) ea += arow[k] * We[k * 64 + d];
  float m = x[(size_t)src * 64 + d] + ea;
  m = fmaxf(m, 0.f);
  atomicAdd(&agg[(size_t)dst * 64 + d], m);
}

// ---------------------------------------------------------------------------
// GINE node MLP, fused: out = relu( relu((x+agg)@W1 + B1) @ W2 + B2 )
// block = 64 nodes, 256 threads; thread t: node t>>2, outputs (t&3)*16..+15
// ---------------------------------------------------------------------------
__global__ __launch_bounds__(256) void gine_mlp_kernel(
    const float* __restrict__ x, const float* __restrict__ agg,
    const float* __restrict__ W1, const float* __restrict__ B1,
    const float* __restrict__ W2, const float* __restrict__ B2,
    float* __restrict__ out, int N)
{
  __shared__ __align__(16) float sW1[64 * 64];
  __shared__ __align__(16) float sW2[64 * 64];
  __shared__ __align__(16) float sBuf[64 * 68];   // in tile, then hidden tile
  int t = threadIdx.x;
  int n0 = blockIdx.x * 64;
  #pragma unroll
  for (int i = 0; i < 16; i++) { int f = t + i * 256; sW1[f] = W1[f]; sW2[f] = W2[f]; }
  #pragma unroll
  for (int i = 0; i < 16; i++) {
    int f = t + i * 256;
    size_t g = (size_t)n0 * 64 + f;
    sBuf[(f >> 6) * 68 + (f & 63)] = x[g] + agg[g];
  }
  __syncthreads();
  int n = t >> 2, kk = t & 3;
  float acc[16];
  #pragma unroll
  for (int j = 0; j < 16; j++) acc[j] = B1[kk * 16 + j];
  #pragma unroll
  for (int d = 0; d < 64; d++) {
    float xv = sBuf[n * 68 + d];
    const float* wrow = &sW1[d * 64 + kk * 16];
    #pragma unroll
    for (int j = 0; j < 16; j++) acc[j] += xv * wrow[j];
  }
  __syncthreads();                 // all sBuf reads done before overwrite
  #pragma unroll
  for (int j = 0; j < 16; j++) sBuf[n * 68 + kk * 16 + j] = fmaxf(acc[j], 0.f);
  __syncthreads();
  #pragma unroll
  for (int j = 0; j < 16; j++) acc[j] = B2[kk * 16 + j];
  #pragma unroll
  for (int d = 0; d < 64; d++) {
    float xv = sBuf[n * 68 + d];
    const float* wrow = &sW2[d * 64 + kk * 16];
    #pragma unroll
    for (int j = 0; j < 16; j++) acc[j] += xv * wrow[j];
  }
  float* op = out + (size_t)(n0 + n) * 64 + kk * 16;
  #pragma unroll
  for (int j = 0; j < 16; j++) op[j] = fmaxf(acc[j], 0.f);   // outer relu fused
}

// ---------------------------------------------------------------------------
// 64x64 projection into head-major layout: Out[h][n][d], h=(t&3), d=j
// ---------------------------------------------------------------------------
__global__ __launch_bounds__(256) void proj1_kernel(
    const float* __restrict__ xin, const float* __restrict__ W,
    const float* __restrict__ Bb, float* __restrict__ Out, int N)
{
  __shared__ __align__(16) float sW[64 * 64];
  __shared__ __align__(16) float sIn[64 * 68];
  int t = threadIdx.x;
  int n0 = blockIdx.x * 64;
  #pragma unroll
  for (int i = 0; i < 16; i++) { int f = t + i * 256; sW[f] = W[f]; }
  #pragma unroll
  for (int i = 0; i < 16; i++) {
    int f = t + i * 256;
    sIn[(f >> 6) * 68 + (f & 63)] = xin[(size_t)n0 * 64 + f];
  }
  __syncthreads();
  int n = t >> 2, kk = t & 3;
  float acc[16];
  #pragma unroll
  for (int j = 0; j < 16; j++) acc[j] = Bb[kk * 16 + j];
  #pragma unroll
  for (int d = 0; d < 64; d++) {
    float xv = sIn[n * 68 + d];
    const float* wrow = &sW[d * 64 + kk * 16];
    #pragma unroll
    for (int j = 0; j < 16; j++) acc[j] += xv * wrow[j];
  }
  float* op = Out + (size_t)kk * N * 16 + (size_t)(n0 + n) * 16;
  #pragma unroll
  for (int j = 0; j < 16; j++) op[j] = acc[j];
}

// ---------------------------------------------------------------------------
// Flash-style cross attention. Q,K,V in [H][N][16]; out [Nq][64].
// block = (64 queries, 1 head), 256 threads. thread t: q=t>>2, kk=t&3.
// Score phase: 16 keys (kk*16..+15) per thread; PV phase: dims kk*4..+3.
// Online softmax state (m,s) replicated across the 4 lanes of a q-group.
// ---------------------------------------------------------------------------
__global__ __launch_bounds__(256) void attn_kernel(
    const float* __restrict__ Q, const float* __restrict__ K,
    const float* __restrict__ V, float* __restrict__ out, int Nq, int Nk)
{
  __shared__ __align__(16) float sK[64 * 20];
  __shared__ __align__(16) float sV[64 * 20];
  __shared__ __align__(16) float sP[64 * 68];
  const int t = threadIdx.x;
  const int h = blockIdx.y;
  const int q0 = blockIdx.x * 64;
  const int q = t >> 2, kk = t & 3;
  const float* Qh = Q + ((size_t)h * Nq + q0) * 16;
  const float* Kh = K + (size_t)h * Nk * 16;
  const float* Vh = V + (size_t)h * Nk * 16;
  float qr[16];
  #pragma unroll
  for (int j = 0; j < 16; j++) qr[j] = Qh[q * 16 + j] * 0.25f;  // fold 1/sqrt(16)
  float m = -1e30f, s = 0.f;
  float o0 = 0.f, o1 = 0.f, o2 = 0.f, o3 = 0.f;

  for (int k0 = 0; k0 < Nk; k0 += 64) {
    #pragma unroll
    for (int i = 0; i < 4; i++) {
      int f = t + i * 256;                       // 0..1023, coalesced
      sK[(f >> 4) * 20 + (f & 15)] = Kh[(size_t)k0 * 16 + f];
      sV[(f >> 4) * 20 + (f & 15)] = Vh[(size_t)k0 * 16 + f];
    }
    __syncthreads();

    float sc[16];
    float tmax = -1e30f;
    #pragma unroll
    for (int j = 0; j < 16; j++) {
      const float* kp = &sK[(kk * 16 + j) * 20];
      float acc = 0.f;
      #pragma unroll
      for (int d = 0; d < 16; d++) acc += qr[d] * kp[d];
      sc[j] = acc;
      tmax = fmaxf(tmax, acc);
    }
    tmax = fmaxf(tmax, __shfl_xor(tmax, 1));
    tmax = fmaxf(tmax, __shfl_xor(tmax, 2));
    float mnew = fmaxf(m, tmax);
    float alpha = __expf(m - mnew);
    float psum = 0.f;
    #pragma unroll
    for (int j = 0; j < 16; j++) {
      float p = __expf(sc[j] - mnew);
      sP[q * 68 + kk * 16 + j] = p;
      psum += p;
    }
    psum += __shfl_xor(psum, 1);
    psum += __shfl_xor(psum, 2);
    s = s * alpha + psum;
    m = mnew;
    o0 *= alpha; o1 *= alpha; o2 *= alpha; o3 *= alpha;
    __syncthreads();                               // sP visible to whole block

    #pragma unroll 4
    for (int k = 0; k < 64; k++) {
      float p = sP[q * 68 + k];
      const float* vp = &sV[k * 20 + kk * 4];
      o0 += p * vp[0]; o1 += p * vp[1]; o2 += p * vp[2]; o3 += p * vp[3];
    }
    __syncthreads();                               // before next tile overwrite
  }
  float inv = 1.f / s;
  float* op = out + (size_t)(q0 + q) * 64 + h * 16 + kk * 4;
  op[0] = o0 * inv; op[1] = o1 * inv; op[2] = o2 * inv; op[3] = o3 * inv;
}

// ---------------------------------------------------------------------------
// LayerNorm(h + a) * g + b ; one wave per 64-dim row, population variance
// ---------------------------------------------------------------------------
__global__ __launch_bounds__(256) void ln_add_kernel(
    const float* __restrict__ h, const float* __restrict__ a,
    const float* __restrict__ g, const float* __restrict__ bb,
    float* __restrict__ out, int N)
{
  int idx = blockIdx.x * 256 + threadIdx.x;
  if (idx >= N * 64) return;
  int d = idx & 63;
  float v = h[idx] + a[idx];
  float sm = v;
  #pragma unroll
  for (int o = 1; o < 64; o <<= 1) sm += __shfl_xor(sm, o);
  float mu = sm * 0.015625f;
  float c = v - mu;
  float q = c * c;
  #pragma unroll
  for (int o = 1; o < 64; o <<= 1) q += __shfl_xor(q, o);
  float var = q * 0.015625f;
  out[idx] = c * rsqrtf(var + 1e-5f) * g[d] + bb[d];
}

// ---------------------------------------------------------------------------
// segment-sum pooling into [32][128] (+ per-graph counts at cnt[cntOff+seg])
// ---------------------------------------------------------------------------
__global__ __launch_bounds__(256) void pool_acc_kernel(
    const float* __restrict__ x, const int* __restrict__ batch,
    float* __restrict__ sums, float* __restrict__ cnt, int N, int colOff, int cntOff)
{
  int idx = blockIdx.x * 256 + threadIdx.x;
  if (idx >= N * 64) return;
  int n = idx >> 6, d = idx & 63;
  int seg = batch[n];
  atomicAdd(&sums[seg * 128 + colOff + d], x[idx]);
  if (d == 0) atomicAdd(&cnt[cntOff + seg], 1.0f);
}

// ---------------------------------------------------------------------------
// final head: z = sums/counts; h1 = relu(z@fc1+b1); out = sigmoid(h1@fc2+b2)
// ---------------------------------------------------------------------------
__global__ __launch_bounds__(256) void final_kernel(
    const float* __restrict__ sums, const float* __restrict__ cnt,
    const float* __restrict__ fc1w, const float* __restrict__ fc1b,
    const float* __restrict__ fc2w, const float* __restrict__ fc2b,
    float* __restrict__ out)
{
  __shared__ float z[32 * 128];
  __shared__ float h1[32 * 64];
  int t = threadIdx.x;
  for (int f = t; f < 32 * 128; f += 256) {
    int s = f >> 7, j = f & 127;
    float c = cnt[(j >> 6) * 32 + s];
    z[f] = sums[f] / fmaxf(c, 1.f);
  }
  __syncthreads();
  for (int f = t; f < 32 * 64; f += 256) {
    int s = f >> 6, o = f & 63;
    float acc = fc1b[o];
    for (int j = 0; j < 128; j++) acc += z[s * 128 + j] * fc1w[j * 64 + o];
    h1[f] = fmaxf(acc, 0.f);
  }
  __syncthreads();
  if (t < 32) {
    float acc = fc2b[0];
    for (int o = 0; o < 64; o++) acc += h1[t * 64 + o] * fc2w[o];
    out[t] = 1.f / (1.f + __expf(-acc));
  }
}

// ---------------------------------------------------------------------------
extern "C" void kernel_launch(void* const* d_in, const int* in_sizes, int n_in,
                              void* d_out, int out_size, void* d_ws, size_t ws_size,
                              hipStream_t stream)
{
  (void)in_sizes; (void)n_in; (void)out_size; (void)ws_size;
  const float* mol_x          = (const float*)d_in[0];
  const float* prot_x         = (const float*)d_in[1];
  const float* mol_edge_attr  = (const float*)d_in[2];
  const float* prot_edge_attr = (const float*)d_in[3];
  const float* inm_w = (const float*)d_in[4];
  const float* inm_b = (const float*)d_in[5];
  const float* inp_w = (const float*)d_in[6];
  const float* inp_b = (const float*)d_in[7];
  const float* iem_w = (const float*)d_in[8];
  const float* iem_b = (const float*)d_in[9];
  const float* iep_w = (const float*)d_in[10];
  const float* iep_b = (const float*)d_in[11];
  const float* gm_w1 = (const float*)d_in[12];
  const float* gm_b1 = (const float*)d_in[13];
  const float* gm_w2 = (const float*)d_in[14];
  const float* gm_b2 = (const float*)d_in[15];
  const float* gp_w1 = (const float*)d_in[16];
  const float* gp_b1 = (const float*)d_in[17];
  const float* gp_w2 = (const float*)d_in[18];
  const float* gp_b2 = (const float*)d_in[19];
  const float* m2p_w = (const float*)d_in[20];
  const float* m2p_b = (const float*)d_in[21];
  const float* p2m_w = (const float*)d_in[22];
  const float* p2m_b = (const float*)d_in[23];
  const float* lnm_g = (const float*)d_in[24];
  const float* lnm_b = (const float*)d_in[25];
  const float* lnp_g = (const float*)d_in[26];
  const float* lnp_b = (const float*)d_in[27];
  const float* fc1_w = (const float*)d_in[28];
  const float* fc1_b = (const float*)d_in[29];
  const float* fc2_w = (const float*)d_in[30];
  const float* fc2_b = (const float*)d_in[31];
  const int* mol_ei     = (const int*)d_in[32];
  const int* prot_ei    = (const int*)d_in[33];
  const int* mol_batch  = (const int*)d_in[34];
  const int* prot_batch = (const int*)d_in[35];

  const int NM = 4096, NP = 8192, EM = 65536, EP = 262144;

  float* ws = (float*)d_ws;
  size_t off = 0;
  auto nxt = [&](size_t n) { float* p = ws + off; off += n; return p; };
  float* x_mol    = nxt((size_t)NM * 64);
  float* x_prot   = nxt((size_t)NP * 64);
  float* agg_mol  = nxt((size_t)NM * 64);
  float* agg_prot = nxt((size_t)NP * 64);
  float* h_mol    = nxt((size_t)NM * 64);
  float* h_prot   = nxt((size_t)NP * 64);
  float* a_mol    = nxt((size_t)NM * 64);
  float* a_prot   = nxt((size_t)NP * 64);
  float* Qm = nxt((size_t)NM * 64);
  float* Km = nxt((size_t)NM * 64);
  float* Vm = nxt((size_t)NM * 64);
  float* Qp = nxt((size_t)NP * 64);
  float* Kp = nxt((size_t)NP * 64);
  float* Vp = nxt((size_t)NP * 64);
  float* pool = nxt(32 * 128);
  float* cnt  = nxt(64);

  init_embed_kernel<<<NM * 64 / 256, 256, 0, stream>>>(mol_x, inm_w, inm_b, x_mol, NM, 11);
  init_embed_kernel<<<NP * 64 / 256, 256, 0, stream>>>(prot_x, inp_w, inp_b, x_prot, NP, 15);

  for (int l = 0; l < 3; l++) {
    hipMemsetAsync(agg_mol, 0, (size_t)NM * 64 * 4, stream);
    hipMemsetAsync(agg_prot, 0, (size_t)NP * 64 * 4, stream);
    gine_msg_kernel<<<EM * 64 / 256, 256, 0, stream>>>(x_mol, mol_edge_attr, iem_w, iem_b, mol_ei, agg_mol, EM);
    gine_msg_kernel<<<EP * 64 / 256, 256, 0, stream>>>(x_prot, prot_edge_attr, iep_w, iep_b, prot_ei, agg_prot, EP);
    gine_mlp_kernel<<<NM / 64, 256, 0, stream>>>(x_mol, agg_mol, gm_w1 + l * 4096, gm_b1 + l * 64,
                                                 gm_w2 + l * 4096, gm_b2 + l * 64, h_mol, NM);
    gine_mlp_kernel<<<NP / 64, 256, 0, stream>>>(x_prot, agg_prot, gp_w1 + l * 4096, gp_b1 + l * 64,
                                                 gp_w2 + l * 4096, gp_b2 + l * 64, h_prot, NP);
    // m2p attention: Q from mol (m2p W[0]), K/V from prot (m2p W[1],W[2])
    // p2m attention: Q from prot (p2m W[0]), K/V from mol (p2m W[1],W[2])
    proj1_kernel<<<NM / 64, 256, 0, stream>>>(h_mol, m2p_w + (l * 3 + 0) * 4096, m2p_b + (l * 3 + 0) * 64, Qm, NM);
    proj1_kernel<<<NM / 64, 256, 0, stream>>>(h_mol, p2m_w + (l * 3 + 1) * 4096, p2m_b + (l * 3 + 1) * 64, Km, NM);
    proj1_kernel<<<NM / 64, 256, 0, stream>>>(h_mol, p2m_w + (l * 3 + 2) * 4096, p2m_b + (l * 3 + 2) * 64, Vm, NM);
    proj1_kernel<<<NP / 64, 256, 0, stream>>>(h_prot, p2m_w + (l * 3 + 0) * 4096, p2m_b + (l * 3 + 0) * 64, Qp, NP);
    proj1_kernel<<<NP / 64, 256, 0, stream>>>(h_prot, m2p_w + (l * 3 + 1) * 4096, m2p_b + (l * 3 + 1) * 64, Kp, NP);
    proj1_kernel<<<NP / 64, 256, 0, stream>>>(h_prot, m2p_w + (l * 3 + 2) * 4096, m2p_b + (l * 3 + 2) * 64, Vp, NP);
    attn_kernel<<<dim3(NM / 64, 4), 256, 0, stream>>>(Qm, Kp, Vp, a_mol, NM, NP);
    attn_kernel<<<dim3(NP / 64, 4), 256, 0, stream>>>(Qp, Km, Vm, a_prot, NP, NM);
    ln_add_kernel<<<NM * 64 / 256, 256, 0, stream>>>(h_mol, a_mol, lnm_g + l * 64, lnm_b + l * 64, x_mol, NM);
    ln_add_kernel<<<NP * 64 / 256, 256, 0, stream>>>(h_prot, a_prot, lnp_g + l * 64, lnp_b + l * 64, x_prot, NP);
  }

  hipMemsetAsync(pool, 0, 32 * 128 * 4, stream);
  hipMemsetAsync(cnt, 0, 64 * 4, stream);
  pool_acc_kernel<<<NM * 64 / 256, 256, 0, stream>>>(x_mol, mol_batch, pool, cnt, NM, 0, 0);
  pool_acc_kernel<<<NP * 64 / 256, 256, 0, stream>>>(x_prot, prot_batch, pool, cnt, NP, 64, 32);
  final_kernel<<<1, 256, 0, stream>>>(pool, cnt, fc1_w, fc1_b, fc2_w, fc2_b, (float*)d_out);
}

// Round 3
// 1182.734 us; speedup vs baseline: 2.7310x; 2.7310x over previous
//
#include <hip/hip_runtime.h>
#include <cstddef>

typedef _Float16 f16x4 __attribute__((ext_vector_type(4)));
typedef float f32x4 __attribute__((ext_vector_type(4)));

__device__ __forceinline__ f32x4 mfma16(f16x4 a, f16x4 b, f32x4 c) {
  return __builtin_amdgcn_mfma_f32_16x16x16f16(a, b, c, 0, 0, 0);
}

// ---------------------------------------------------------------------------
// init node embedding: out[n][o] = b[o] + sum_k in[n][k] * W[k][o]
// ---------------------------------------------------------------------------
__global__ __launch_bounds__(256) void init_embed_kernel(
    const float* __restrict__ in, const float* __restrict__ W,
    const float* __restrict__ b, float* __restrict__ out, int N, int Kin)
{
  int idx = blockIdx.x * 256 + threadIdx.x;
  if (idx >= N * 64) return;
  int n = idx >> 6, o = idx & 63;
  float acc = b[o];
  const float* row = in + (size_t)n * Kin;
  for (int k = 0; k < Kin; k++) acc += row[k] * W[k * 64 + o];
  out[idx] = acc;
}

// ---------------------------------------------------------------------------
// GINE message + aggregate: agg[dst] += relu(x[src] + (attr @ We + be))
// ---------------------------------------------------------------------------
__global__ __launch_bounds__(256) void gine_msg_kernel(
    const float* __restrict__ x, const float* __restrict__ attr,
    const float* __restrict__ We, const float* __restrict__ be,
    const int* __restrict__ ei, float* __restrict__ agg, int E)
{
  int idx = blockIdx.x * 256 + threadIdx.x;
  if (idx >= E * 64) return;
  int e = idx >> 6, d = idx & 63;
  int src = ei[e];
  int dst = ei[E + e];
  float ea = be[d];
  const float* arow = attr + (size_t)e * 10;
  #pragma unroll
  for (int k = 0; k < 10; k++) ea += arow[k] * We[k * 64 + d];
  float m = x[(size_t)src * 64 + d] + ea;
  m = fmaxf(m, 0.f);
  atomicAdd(&agg[(size_t)dst * 64 + d], m);
}

// ---------------------------------------------------------------------------
// GINE node MLP, fused: out = relu( relu((x+agg)@W1 + B1) @ W2 + B2 )
// ---------------------------------------------------------------------------
__global__ __launch_bounds__(256) void gine_mlp_kernel(
    const float* __restrict__ x, const float* __restrict__ agg,
    const float* __restrict__ W1, const float* __restrict__ B1,
    const float* __restrict__ W2, const float* __restrict__ B2,
    float* __restrict__ out, int N)
{
  __shared__ __align__(16) float sW1[64 * 64];
  __shared__ __align__(16) float sW2[64 * 64];
  __shared__ __align__(16) float sBuf[64 * 68];
  int t = threadIdx.x;
  int n0 = blockIdx.x * 64;
  #pragma unroll
  for (int i = 0; i < 16; i++) { int f = t + i * 256; sW1[f] = W1[f]; sW2[f] = W2[f]; }
  #pragma unroll
  for (int i = 0; i < 16; i++) {
    int f = t + i * 256;
    size_t g = (size_t)n0 * 64 + f;
    sBuf[(f >> 6) * 68 + (f & 63)] = x[g] + agg[g];
  }
  __syncthreads();
  int n = t >> 2, kk = t & 3;
  float acc[16];
  #pragma unroll
  for (int j = 0; j < 16; j++) acc[j] = B1[kk * 16 + j];
  #pragma unroll
  for (int d = 0; d < 64; d++) {
    float xv = sBuf[n * 68 + d];
    const float* wrow = &sW1[d * 64 + kk * 16];
    #pragma unroll
    for (int j = 0; j < 16; j++) acc[j] += xv * wrow[j];
  }
  __syncthreads();
  #pragma unroll
  for (int j = 0; j < 16; j++) sBuf[n * 68 + kk * 16 + j] = fmaxf(acc[j], 0.f);
  __syncthreads();
  #pragma unroll
  for (int j = 0; j < 16; j++) acc[j] = B2[kk * 16 + j];
  #pragma unroll
  for (int d = 0; d < 64; d++) {
    float xv = sBuf[n * 68 + d];
    const float* wrow = &sW2[d * 64 + kk * 16];
    #pragma unroll
    for (int j = 0; j < 16; j++) acc[j] += xv * wrow[j];
  }
  float* op = out + (size_t)(n0 + n) * 64 + kk * 16;
  #pragma unroll
  for (int j = 0; j < 16; j++) op[j] = fmaxf(acc[j], 0.f);
}

// ---------------------------------------------------------------------------
// 64x64 projection -> fp16 head-major Out[h][n][16], optional scale (Q: 0.25)
// ---------------------------------------------------------------------------
__global__ __launch_bounds__(256) void proj_qk_kernel(
    const float* __restrict__ xin, const float* __restrict__ W,
    const float* __restrict__ Bb, _Float16* __restrict__ Out, int N, float scale)
{
  __shared__ __align__(16) float sW[64 * 64];
  __shared__ __align__(16) float sIn[64 * 68];
  int t = threadIdx.x;
  int n0 = blockIdx.x * 64;
  #pragma unroll
  for (int i = 0; i < 16; i++) { int f = t + i * 256; sW[f] = W[f]; }
  #pragma unroll
  for (int i = 0; i < 16; i++) {
    int f = t + i * 256;
    sIn[(f >> 6) * 68 + (f & 63)] = xin[(size_t)n0 * 64 + f];
  }
  __syncthreads();
  int n = t >> 2, kk = t & 3;
  float acc[16];
  #pragma unroll
  for (int j = 0; j < 16; j++) acc[j] = Bb[kk * 16 + j];
  #pragma unroll
  for (int d = 0; d < 64; d++) {
    float xv = sIn[n * 68 + d];
    const float* wrow = &sW[d * 64 + kk * 16];
    #pragma unroll
    for (int j = 0; j < 16; j++) acc[j] += xv * wrow[j];
  }
  _Float16 tmp[16];
  #pragma unroll
  for (int j = 0; j < 16; j++) tmp[j] = (_Float16)(acc[j] * scale);
  float4* dst = (float4*)(Out + ((size_t)kk * N + n0 + n) * 16);
  dst[0] = ((float4*)tmp)[0];
  dst[1] = ((float4*)tmp)[1];
}

// ---------------------------------------------------------------------------
// V projection -> fp16 TRANSPOSED Out[h][16][N]  (for Vt A-frags in attention)
// ---------------------------------------------------------------------------
__global__ __launch_bounds__(256) void proj_v_kernel(
    const float* __restrict__ xin, const float* __restrict__ W,
    const float* __restrict__ Bb, _Float16* __restrict__ Out, int N)
{
  __shared__ __align__(16) float sW[64 * 64];
  __shared__ __align__(16) float sIn[64 * 68];
  int t = threadIdx.x;
  int n0 = blockIdx.x * 64;
  #pragma unroll
  for (int i = 0; i < 16; i++) { int f = t + i * 256; sW[f] = W[f]; }
  #pragma unroll
  for (int i = 0; i < 16; i++) {
    int f = t + i * 256;
    sIn[(f >> 6) * 68 + (f & 63)] = xin[(size_t)n0 * 64 + f];
  }
  __syncthreads();
  int n = t >> 2, kk = t & 3;
  float acc[16];
  #pragma unroll
  for (int j = 0; j < 16; j++) acc[j] = Bb[kk * 16 + j];
  #pragma unroll
  for (int d = 0; d < 64; d++) {
    float xv = sIn[n * 68 + d];
    const float* wrow = &sW[d * 64 + kk * 16];
    #pragma unroll
    for (int j = 0; j < 16; j++) acc[j] += xv * wrow[j];
  }
  #pragma unroll
  for (int j = 0; j < 16; j++)
    Out[((size_t)kk * 16 + j) * N + (n0 + n)] = (_Float16)acc[j];
}

// ---------------------------------------------------------------------------
// MFMA flash cross-attention. Q,K: fp16 [H][N][16] (Q pre-scaled by 0.25),
// Vt: fp16 [H][16][N]. out: fp32 [Nq][64]. LDS-free main loop.
// Block = 16 queries x 1 head, 4 waves; wave w owns keys w*64+256*i.
// Scores computed TRANSPOSED (D[key][q]) so exp(D) feeds the PV MFMA's
// B operand directly (C/D layout == B layout, reg<->k). O^T accumulated,
// cross-wave flash-combine via LDS at the end.
// ---------------------------------------------------------------------------
__global__ __launch_bounds__(256) void attn_mfma_kernel(
    const _Float16* __restrict__ Q, const _Float16* __restrict__ K,
    const _Float16* __restrict__ Vt, float* __restrict__ out, int Nq, int Nk)
{
  const int h = blockIdx.y;
  const int q0 = blockIdx.x * 16;
  const int t = threadIdx.x;
  const int wave = t >> 6, lane = t & 63;
  const int l16 = lane & 15, quad = lane >> 4;

  // Q B-frag: B[k=d=quad*4+i][n=q=l16]  (held for whole kernel)
  const f16x4 qf = *(const f16x4*)(Q + ((size_t)h * Nq + q0 + l16) * 16 + quad * 4);
  const _Float16* Kh = K + (size_t)h * Nk * 16;
  const _Float16* Vh = Vt + ((size_t)h * 16 + l16) * Nk;  // row d = l16

  f32x4 oacc = {0.f, 0.f, 0.f, 0.f};
  float mrun = -1e30f, lrun = 0.f;
  const f32x4 zero = {0.f, 0.f, 0.f, 0.f};

  for (int kb = wave * 64; kb < Nk; kb += 256) {
    f16x4 kf[4], vf[4];
    #pragma unroll
    for (int c = 0; c < 4; c++) {
      // K A-frag: A[m=key=l16][k=d=quad*4+i]
      kf[c] = *(const f16x4*)(Kh + (size_t)(kb + c * 16 + l16) * 16 + quad * 4);
      // V^T A-frag: A[m=d=l16][k=key=quad*4+i]
      vf[c] = *(const f16x4*)(Vh + kb + c * 16 + quad * 4);
    }
    f32x4 s[4];
    #pragma unroll
    for (int c = 0; c < 4; c++) s[c] = mfma16(kf[c], qf, zero);

    float tm = -1e30f;
    #pragma unroll
    for (int c = 0; c < 4; c++)
      #pragma unroll
      for (int r = 0; r < 4; r++) tm = fmaxf(tm, s[c][r]);
    tm = fmaxf(tm, __shfl_xor(tm, 16));
    tm = fmaxf(tm, __shfl_xor(tm, 32));
    float mnew = fmaxf(mrun, tm);
    float alpha = __expf(mrun - mnew);
    float psum = 0.f;
    f16x4 pf[4];
    #pragma unroll
    for (int c = 0; c < 4; c++)
      #pragma unroll
      for (int r = 0; r < 4; r++) {
        float p = __expf(s[c][r] - mnew);
        psum += p;
        pf[c][r] = (_Float16)p;
      }
    psum += __shfl_xor(psum, 16);
    psum += __shfl_xor(psum, 32);
    lrun = lrun * alpha + psum;
    mrun = mnew;
    #pragma unroll
    for (int r = 0; r < 4; r++) oacc[r] *= alpha;
    // PV: O^T += V^T-chunk * P^T-chunk  (pf IS the B-frag already)
    #pragma unroll
    for (int c = 0; c < 4; c++) oacc = mfma16(vf[c], pf[c], oacc);
  }

  // cross-wave flash combine
  __shared__ float sO[4][16][16];
  __shared__ float sm[4][16];
  __shared__ float sl[4][16];
  #pragma unroll
  for (int r = 0; r < 4; r++) sO[wave][quad * 4 + r][l16] = oacc[r];
  if (quad == 0) { sm[wave][l16] = mrun; sl[wave][l16] = lrun; }
  __syncthreads();
  {
    int q = t >> 4, d = t & 15;
    float M = sm[0][q];
    #pragma unroll
    for (int w = 1; w < 4; w++) M = fmaxf(M, sm[w][q]);
    float acc = 0.f, L = 0.f;
    #pragma unroll
    for (int w = 0; w < 4; w++) {
      float f = __expf(sm[w][q] - M);
      acc += f * sO[w][d][q];
      L += f * sl[w][q];
    }
    out[(size_t)(q0 + q) * 64 + h * 16 + d] = acc / L;
  }
}

// ---------------------------------------------------------------------------
// LayerNorm(h + a) * g + b
// ---------------------------------------------------------------------------
__global__ __launch_bounds__(256) void ln_add_kernel(
    const float* __restrict__ h, const float* __restrict__ a,
    const float* __restrict__ g, const float* __restrict__ bb,
    float* __restrict__ out, int N)
{
  int idx = blockIdx.x * 256 + threadIdx.x;
  if (idx >= N * 64) return;
  int d = idx & 63;
  float v = h[idx] + a[idx];
  float sm = v;
  #pragma unroll
  for (int o = 1; o < 64; o <<= 1) sm += __shfl_xor(sm, o);
  float mu = sm * 0.015625f;
  float c = v - mu;
  float q = c * c;
  #pragma unroll
  for (int o = 1; o < 64; o <<= 1) q += __shfl_xor(q, o);
  float var = q * 0.015625f;
  out[idx] = c * rsqrtf(var + 1e-5f) * g[d] + bb[d];
}

// ---------------------------------------------------------------------------
// segment-sum pooling
// ---------------------------------------------------------------------------
__global__ __launch_bounds__(256) void pool_acc_kernel(
    const float* __restrict__ x, const int* __restrict__ batch,
    float* __restrict__ sums, float* __restrict__ cnt, int N, int colOff, int cntOff)
{
  int idx = blockIdx.x * 256 + threadIdx.x;
  if (idx >= N * 64) return;
  int n = idx >> 6, d = idx & 63;
  int seg = batch[n];
  atomicAdd(&sums[seg * 128 + colOff + d], x[idx]);
  if (d == 0) atomicAdd(&cnt[cntOff + seg], 1.0f);
}

// ---------------------------------------------------------------------------
// final head
// ---------------------------------------------------------------------------
__global__ __launch_bounds__(256) void final_kernel(
    const float* __restrict__ sums, const float* __restrict__ cnt,
    const float* __restrict__ fc1w, const float* __restrict__ fc1b,
    const float* __restrict__ fc2w, const float* __restrict__ fc2b,
    float* __restrict__ out)
{
  __shared__ float z[32 * 128];
  __shared__ float h1[32 * 64];
  int t = threadIdx.x;
  for (int f = t; f < 32 * 128; f += 256) {
    int s = f >> 7, j = f & 127;
    float c = cnt[(j >> 6) * 32 + s];
    z[f] = sums[f] / fmaxf(c, 1.f);
  }
  __syncthreads();
  for (int f = t; f < 32 * 64; f += 256) {
    int s = f >> 6, o = f & 63;
    float acc = fc1b[o];
    for (int j = 0; j < 128; j++) acc += z[s * 128 + j] * fc1w[j * 64 + o];
    h1[f] = fmaxf(acc, 0.f);
  }
  __syncthreads();
  if (t < 32) {
    float acc = fc2b[0];
    for (int o = 0; o < 64; o++) acc += h1[t * 64 + o] * fc2w[o];
    out[t] = 1.f / (1.f + __expf(-acc));
  }
}

// ---------------------------------------------------------------------------
extern "C" void kernel_launch(void* const* d_in, const int* in_sizes, int n_in,
                              void* d_out, int out_size, void* d_ws, size_t ws_size,
                              hipStream_t stream)
{
  (void)in_sizes; (void)n_in; (void)out_size; (void)ws_size;
  const float* mol_x          = (const float*)d_in[0];
  const float* prot_x         = (const float*)d_in[1];
  const float* mol_edge_attr  = (const float*)d_in[2];
  const float* prot_edge_attr = (const float*)d_in[3];
  const float* inm_w = (const float*)d_in[4];
  const float* inm_b = (const float*)d_in[5];
  const float* inp_w = (const float*)d_in[6];
  const float* inp_b = (const float*)d_in[7];
  const float* iem_w = (const float*)d_in[8];
  const float* iem_b = (const float*)d_in[9];
  const float* iep_w = (const float*)d_in[10];
  const float* iep_b = (const float*)d_in[11];
  const float* gm_w1 = (const float*)d_in[12];
  const float* gm_b1 = (const float*)d_in[13];
  const float* gm_w2 = (const float*)d_in[14];
  const float* gm_b2 = (const float*)d_in[15];
  const float* gp_w1 = (const float*)d_in[16];
  const float* gp_b1 = (const float*)d_in[17];
  const float* gp_w2 = (const float*)d_in[18];
  const float* gp_b2 = (const float*)d_in[19];
  const float* m2p_w = (const float*)d_in[20];
  const float* m2p_b = (const float*)d_in[21];
  const float* p2m_w = (const float*)d_in[22];
  const float* p2m_b = (const float*)d_in[23];
  const float* lnm_g = (const float*)d_in[24];
  const float* lnm_b = (const float*)d_in[25];
  const float* lnp_g = (const float*)d_in[26];
  const float* lnp_b = (const float*)d_in[27];
  const float* fc1_w = (const float*)d_in[28];
  const float* fc1_b = (const float*)d_in[29];
  const float* fc2_w = (const float*)d_in[30];
  const float* fc2_b = (const float*)d_in[31];
  const int* mol_ei     = (const int*)d_in[32];
  const int* prot_ei    = (const int*)d_in[33];
  const int* mol_batch  = (const int*)d_in[34];
  const int* prot_batch = (const int*)d_in[35];

  const int NM = 4096, NP = 8192, EM = 65536, EP = 262144;

  float* ws = (float*)d_ws;
  size_t off = 0;
  auto nxt  = [&](size_t n) { float* p = ws + off; off += n; return p; };
  auto nxtH = [&](size_t n) { _Float16* p = (_Float16*)(ws + off); off += (n + 1) / 2; return p; };
  float* x_mol    = nxt((size_t)NM * 64);
  float* x_prot   = nxt((size_t)NP * 64);
  float* agg_mol  = nxt((size_t)NM * 64);
  float* agg_prot = nxt((size_t)NP * 64);
  float* h_mol    = nxt((size_t)NM * 64);
  float* h_prot   = nxt((size_t)NP * 64);
  float* a_mol    = nxt((size_t)NM * 64);
  float* a_prot   = nxt((size_t)NP * 64);
  _Float16* Qm  = nxtH((size_t)NM * 64);
  _Float16* Km  = nxtH((size_t)NM * 64);
  _Float16* Vtm = nxtH((size_t)NM * 64);
  _Float16* Qp  = nxtH((size_t)NP * 64);
  _Float16* Kp  = nxtH((size_t)NP * 64);
  _Float16* Vtp = nxtH((size_t)NP * 64);
  float* pool = nxt(32 * 128);
  float* cnt  = nxt(64);

  init_embed_kernel<<<NM * 64 / 256, 256, 0, stream>>>(mol_x, inm_w, inm_b, x_mol, NM, 11);
  init_embed_kernel<<<NP * 64 / 256, 256, 0, stream>>>(prot_x, inp_w, inp_b, x_prot, NP, 15);

  for (int l = 0; l < 3; l++) {
    (void)hipMemsetAsync(agg_mol, 0, (size_t)NM * 64 * 4, stream);
    (void)hipMemsetAsync(agg_prot, 0, (size_t)NP * 64 * 4, stream);
    gine_msg_kernel<<<EM * 64 / 256, 256, 0, stream>>>(x_mol, mol_edge_attr, iem_w, iem_b, mol_ei, agg_mol, EM);
    gine_msg_kernel<<<EP * 64 / 256, 256, 0, stream>>>(x_prot, prot_edge_attr, iep_w, iep_b, prot_ei, agg_prot, EP);
    gine_mlp_kernel<<<NM / 64, 256, 0, stream>>>(x_mol, agg_mol, gm_w1 + l * 4096, gm_b1 + l * 64,
                                                 gm_w2 + l * 4096, gm_b2 + l * 64, h_mol, NM);
    gine_mlp_kernel<<<NP / 64, 256, 0, stream>>>(x_prot, agg_prot, gp_w1 + l * 4096, gp_b1 + l * 64,
                                                 gp_w2 + l * 4096, gp_b2 + l * 64, h_prot, NP);
    // m2p: Q=mol (m2p W0), K/V=prot (m2p W1,W2); p2m: Q=prot (p2m W0), K/V=mol (p2m W1,W2)
    proj_qk_kernel<<<NM / 64, 256, 0, stream>>>(h_mol, m2p_w + (l * 3 + 0) * 4096, m2p_b + (l * 3 + 0) * 64, Qm, NM, 0.25f);
    proj_qk_kernel<<<NM / 64, 256, 0, stream>>>(h_mol, p2m_w + (l * 3 + 1) * 4096, p2m_b + (l * 3 + 1) * 64, Km, NM, 1.0f);
    proj_v_kernel<<<NM / 64, 256, 0, stream>>>(h_mol, p2m_w + (l * 3 + 2) * 4096, p2m_b + (l * 3 + 2) * 64, Vtm, NM);
    proj_qk_kernel<<<NP / 64, 256, 0, stream>>>(h_prot, p2m_w + (l * 3 + 0) * 4096, p2m_b + (l * 3 + 0) * 64, Qp, NP, 0.25f);
    proj_qk_kernel<<<NP / 64, 256, 0, stream>>>(h_prot, m2p_w + (l * 3 + 1) * 4096, m2p_b + (l * 3 + 1) * 64, Kp, NP, 1.0f);
    proj_v_kernel<<<NP / 64, 256, 0, stream>>>(h_prot, m2p_w + (l * 3 + 2) * 4096, m2p_b + (l * 3 + 2) * 64, Vtp, NP);
    attn_mfma_kernel<<<dim3(NM / 16, 4), 256, 0, stream>>>(Qm, Kp, Vtp, a_mol, NM, NP);
    attn_mfma_kernel<<<dim3(NP / 16, 4), 256, 0, stream>>>(Qp, Km, Vtm, a_prot, NP, NM);
    ln_add_kernel<<<NM * 64 / 256, 256, 0, stream>>>(h_mol, a_mol, lnm_g + l * 64, lnm_b + l * 64, x_mol, NM);
    ln_add_kernel<<<NP * 64 / 256, 256, 0, stream>>>(h_prot, a_prot, lnp_g + l * 64, lnp_b + l * 64, x_prot, NP);
  }

  (void)hipMemsetAsync(pool, 0, 32 * 128 * 4, stream);
  (void)hipMemsetAsync(cnt, 0, 64 * 4, stream);
  pool_acc_kernel<<<NM * 64 / 256, 256, 0, stream>>>(x_mol, mol_batch, pool, cnt, NM, 0, 0);
  pool_acc_kernel<<<NP * 64 / 256, 256, 0, stream>>>(x_prot, prot_batch, pool, cnt, NP, 64, 32);
  final_kernel<<<1, 256, 0, stream>>>(pool, cnt, fc1_w, fc1_b, fc2_w, fc2_b, (float*)d_out);
}